// Round 1
// 213.023 us; speedup vs baseline: 1.0607x; 1.0607x over previous
//
#include <hip/hip_runtime.h>
#include <stdint.h>

typedef unsigned short u16;
typedef __attribute__((ext_vector_type(8))) short short8;
typedef __attribute__((ext_vector_type(4))) short short4v;
typedef __attribute__((ext_vector_type(4))) float floatx4;
typedef __attribute__((ext_vector_type(4))) int intx4;

#define B_ 2
#define N_ 2048
#define E_ 1024
#define H_ 16
#define HD_ 64
#define M_TOT (B_ * N_)   // 4096

__device__ __forceinline__ float bf2f(u16 h) {
    union { unsigned u; float f; } c; c.u = ((unsigned)h) << 16; return c.f;
}
__device__ __forceinline__ u16 f2bf(float f) {
    union { float f; unsigned u; } c; c.f = f;
    unsigned r = c.u + 0x7FFFu + ((c.u >> 16) & 1u);
    return (u16)(r >> 16);
}
__device__ __forceinline__ float silu_f(float x) { return x / (1.f + __expf(-x)); }

template <typename T> __device__ __forceinline__ void store_out(T* p, float v);
template <> __device__ __forceinline__ void store_out<u16>(u16* p, float v)    { *p = f2bf(v); }
template <> __device__ __forceinline__ void store_out<float>(float* p, float v) { *p = v; }

// Direct global->LDS 16B async copy. LDS dest = wave-uniform base + lane*16.
__device__ __forceinline__ void gll16(const void* g, void* l) {
    __builtin_amdgcn_global_load_lds(
        (const __attribute__((address_space(1))) void*)g,
        (__attribute__((address_space(3))) void*)l,
        16, 0, 0);
}

// relu(+pack) four fp32 -> 4 bf16 (round-half-up), order preserved.
__device__ __forceinline__ short4v relu_pack(floatx4 s) {
    union { float f; unsigned u; } c0, c1, c2, c3;
    c0.f = fmaxf(s[0], 0.f); c1.f = fmaxf(s[1], 0.f);
    c2.f = fmaxf(s[2], 0.f); c3.f = fmaxf(s[3], 0.f);
    unsigned lo = __builtin_amdgcn_perm(c1.u + 0x8000u, c0.u + 0x8000u, 0x07060302);
    unsigned hi = __builtin_amdgcn_perm(c3.u + 0x8000u, c2.u + 0x8000u, 0x07060302);
    union { unsigned v[2]; short4v s4; } r; r.v[0] = lo; r.v[1] = hi;
    return r.s4;
}

// ---------------------------------------------------------------------------
// fp32 -> bf16 for x (z=0, 2048 blocks) and 5 weights (z=1..5, 512 blocks).
// ---------------------------------------------------------------------------
__launch_bounds__(256, 4)
__global__ void cvt6(const float* __restrict__ s0, const float* __restrict__ s1,
                     const float* __restrict__ s2, const float* __restrict__ s3,
                     const float* __restrict__ s4, const float* __restrict__ s5,
                     u16* __restrict__ d0, u16* __restrict__ d1,
                     u16* __restrict__ d2, u16* __restrict__ d3,
                     u16* __restrict__ d4, u16* __restrict__ d5)
{
    const int z = blockIdx.z;
    if (z > 0 && blockIdx.x >= E_ * E_ / 2048) return;
    const float* src = (z == 0) ? s0 : (z == 1) ? s1 : (z == 2) ? s2
                     : (z == 3) ? s3 : (z == 4) ? s4 : s5;
    u16* dst         = (z == 0) ? d0 : (z == 1) ? d1 : (z == 2) ? d2
                     : (z == 3) ? d3 : (z == 4) ? d4 : d5;
    const int i = (blockIdx.x * 256 + threadIdx.x) * 8;
    floatx4 a = *(const floatx4*)(src + i);
    floatx4 b = *(const floatx4*)(src + i + 4);
    union { u16 h[8]; intx4 v; } o;
    o.h[0] = f2bf(a[0]); o.h[1] = f2bf(a[1]); o.h[2] = f2bf(a[2]); o.h[3] = f2bf(a[3]);
    o.h[4] = f2bf(b[0]); o.h[5] = f2bf(b[1]); o.h[6] = f2bf(b[2]); o.h[7] = f2bf(b[3]);
    *(intx4*)(dst + i) = o.v;
}

// ---------------------------------------------------------------------------
// GEMM (m97 structure, BK=32): C[M,1024] = act( A @ W^T + bias ) [*osc]
// blockIdx.z selects (W, bias, out, act, scale). Row-major coalesced epilogue
// ONLY (scattered epilogues cause 64x write amplification -- r7: 2 GB).
// Used for the 4 projections (grid (8,32,4) = 1024 blocks, 2 resident/CU).
// ---------------------------------------------------------------------------
template <typename OutT>
__launch_bounds__(256, 2)
__global__ void gemm4(const u16* __restrict__ A,
                      const u16* __restrict__ W0, const u16* __restrict__ W1,
                      const u16* __restrict__ W2, const u16* __restrict__ W3,
                      const float* __restrict__ bi0, const float* __restrict__ bi1,
                      const float* __restrict__ bi2, const float* __restrict__ bi3,
                      OutT* __restrict__ O0, OutT* __restrict__ O1,
                      OutT* __restrict__ O2, OutT* __restrict__ O3,
                      int actmask, int scalemask, int K)
{
    __shared__ u16 a_lds[128 * 32];   // 8 KB, unpadded (gll16 lane order)
    __shared__ u16 b_lds[128 * 32];

    const int z = blockIdx.z;
    const u16* W    = (z == 0) ? W0 : (z == 1) ? W1 : (z == 2) ? W2 : W3;
    const float* Bi = (z == 0) ? bi0 : (z == 1) ? bi1 : (z == 2) ? bi2 : bi3;
    OutT* Out       = (z == 0) ? O0 : (z == 1) ? O1 : (z == 2) ? O2 : O3;
    const bool act = (actmask >> z) & 1;
    const float osc = ((scalemask >> z) & 1) ? 0.125f : 1.0f;

    const int t    = threadIdx.x;
    const int wave = t >> 6, lane = t & 63, quad = lane >> 4, l16 = lane & 15;
    const int wm = wave >> 1, wn = wave & 1;
    const int m0 = blockIdx.y * 128;
    const int n0 = blockIdx.x * 128;

    floatx4 acc[4][4];
    const floatx4 fz = {0.f, 0.f, 0.f, 0.f};
    for (int i = 0; i < 4; i++)
        for (int j = 0; j < 4; j++) acc[i][j] = fz;

    // staging map: thread t -> LDS bytes [t*16, t*16+16) -> row t/4, col (t%4)*8
    const int ar = t >> 2;
    const int ac = (t & 3) * 8;
    const u16* Ag0 = A + (size_t)(m0 + ar) * K + ac;
    const u16* Ag1 = A + (size_t)(m0 + 64 + ar) * K + ac;
    const u16* Bg0 = W + (size_t)(n0 + ar) * K + ac;
    const u16* Bg1 = W + (size_t)(n0 + 64 + ar) * K + ac;
    u16* al0 = a_lds + wave * 512;
    u16* al1 = a_lds + 2048 + wave * 512;
    u16* bl0 = b_lds + wave * 512;
    u16* bl1 = b_lds + 2048 + wave * 512;

    for (int k0 = 0; k0 < K; k0 += 32) {
        __syncthreads();
        gll16(Ag0 + k0, al0);
        gll16(Ag1 + k0, al1);
        gll16(Bg0 + k0, bl0);
        gll16(Bg1 + k0, bl1);
        __syncthreads();

        short8 af[4], bfr[4];
        for (int i = 0; i < 4; i++)
            af[i]  = *(const short8*)&a_lds[(wm * 64 + i * 16 + l16) * 32 + quad * 8];
        for (int j = 0; j < 4; j++)
            bfr[j] = *(const short8*)&b_lds[(wn * 64 + j * 16 + l16) * 32 + quad * 8];
        for (int i = 0; i < 4; i++)
            for (int j = 0; j < 4; j++)
                acc[i][j] = __builtin_amdgcn_mfma_f32_16x16x32_bf16(af[i], bfr[j], acc[i][j], 0, 0, 0);
    }

    float bias_v[4];
    for (int j = 0; j < 4; j++) bias_v[j] = Bi[n0 + wn * 64 + j * 16 + l16];

    for (int i = 0; i < 4; i++) {
        const int row = m0 + wm * 64 + i * 16 + quad * 4;
        for (int j = 0; j < 4; j++) {
            const int col = n0 + wn * 64 + j * 16 + l16;
            for (int r = 0; r < 4; r++) {
                float v = acc[i][j][r] + bias_v[j];
                if (act) v = silu_f(v);
                v *= osc;
                store_out<OutT>(&Out[(size_t)(row + r) * E_ + col], v);
            }
        }
    }
}

// ---------------------------------------------------------------------------
// Output projection GEMM: 64x128 tile (BMxBN), grid (E/128, M/64) = 512 blocks
// -> 2 blocks/CU residency (the 128x128 version at grid=256 was 1 block/CU and
// latency-bound at 50 us: no co-resident block to hide the vmcnt(0) barrier
// drain). Waves split N: wave w owns cols w*32..w*32+31, all 64 rows.
// acc[4][2] per wave, 8 MFMA : 6 ds_read per K-step. fp32 out + bias, no act.
// ---------------------------------------------------------------------------
__launch_bounds__(256, 2)
__global__ void gemm_out(const u16* __restrict__ A, const u16* __restrict__ W,
                         const float* __restrict__ Bi, float* __restrict__ Out,
                         int K)
{
    __shared__ u16 a_lds[64 * 32];    // 4 KB
    __shared__ u16 b_lds[128 * 32];   // 8 KB

    const int t    = threadIdx.x;
    const int wave = t >> 6, lane = t & 63, quad = lane >> 4, l16 = lane & 15;
    const int m0 = blockIdx.y * 64;
    const int n0 = blockIdx.x * 128;

    floatx4 acc[4][2];
    const floatx4 fz = {0.f, 0.f, 0.f, 0.f};
    for (int i = 0; i < 4; i++)
        for (int j = 0; j < 2; j++) acc[i][j] = fz;

    // staging map: thread t -> LDS bytes [t*16, t*16+16) -> row t/4, col (t%4)*8
    const int ar = t >> 2;
    const int ac = (t & 3) * 8;
    const u16* Ag0 = A + (size_t)(m0 + ar) * K + ac;        // A rows 0..63
    const u16* Bg0 = W + (size_t)(n0 + ar) * K + ac;        // W rows 0..63
    const u16* Bg1 = W + (size_t)(n0 + 64 + ar) * K + ac;   // W rows 64..127
    u16* al0 = a_lds + wave * 512;
    u16* bl0 = b_lds + wave * 512;
    u16* bl1 = b_lds + 2048 + wave * 512;

    for (int k0 = 0; k0 < K; k0 += 32) {
        __syncthreads();
        gll16(Ag0 + k0, al0);
        gll16(Bg0 + k0, bl0);
        gll16(Bg1 + k0, bl1);
        __syncthreads();

        short8 af[4], bfr[2];
        for (int i = 0; i < 4; i++)
            af[i]  = *(const short8*)&a_lds[(i * 16 + l16) * 32 + quad * 8];
        for (int j = 0; j < 2; j++)
            bfr[j] = *(const short8*)&b_lds[(wave * 32 + j * 16 + l16) * 32 + quad * 8];
        for (int i = 0; i < 4; i++)
            for (int j = 0; j < 2; j++)
                acc[i][j] = __builtin_amdgcn_mfma_f32_16x16x32_bf16(af[i], bfr[j], acc[i][j], 0, 0, 0);
    }

    float bias_v[2];
    for (int j = 0; j < 2; j++) bias_v[j] = Bi[n0 + wave * 32 + j * 16 + l16];

    for (int i = 0; i < 4; i++) {
        const int row = m0 + i * 16 + quad * 4;
        for (int j = 0; j < 2; j++) {
            const int col = n0 + wave * 32 + j * 16 + l16;
            for (int r = 0; r < 4; r++)
                Out[(size_t)(row + r) * E_ + col] = acc[i][j][r] + bias_v[j];
        }
    }
}

// ---------------------------------------------------------------------------
// Attention v6: O = relu(Q K^T) @ V, Q pre-scaled 1/8. KSPLIT 4->2: grid
// (8,32,2)=512 blocks still fills 2-blocks/CU residency, but partial-output
// traffic halves (attn writes 16 MB not 32; ln_gate reads 16 MB; Q re-fetch
// halves). vtrans fused into staging: V read row-major coalesced, transposed
// into padded [64][72] LDS via 16 ds_write_b16/thread.
// QK: S^T = K Q^T (x32), K rows ROW-PERMUTED (LK=72) so two 16-key C-tiles
// relu_pack in-register into the exact x32 PV A-frag (full-rate x32 PV).
// Block: 256 q (4 waves x 64 q) x (b,h) x key-chunk z, 64-key tiles.
// ---------------------------------------------------------------------------
#define LK 72
#define LV 72
#define KSPLIT 2
#define KCHUNK (N_ / KSPLIT)    // 1024 keys per z

__launch_bounds__(256, 2)
__global__ void attn(const u16* __restrict__ Q, const u16* __restrict__ Kk,
                     const u16* __restrict__ V,
                     u16* __restrict__ P0, u16* __restrict__ P1)
{
    __shared__ u16 k_lds[64 * LK];    // row-permuted [keyslot][d]
    __shared__ u16 v_lds[64 * LV];    // [d][key], padded stride

    const int bh = blockIdx.y;
    const int b = bh >> 4, h = bh & 15;
    const int z = blockIdx.z;
    u16* __restrict__ Oa = (z == 0) ? P0 : P1;
    const int key_base = z * KCHUNK;

    const int t = threadIdx.x;
    const int wave = t >> 6, lane = t & 63, quad = lane >> 4, l16 = lane & 15;
    const int q0 = blockIdx.x * 256 + wave * 64;
    const size_t base = (size_t)b * N_ * E_ + h * HD_;

    // Q fragments (pre-scaled 1/8): B-layout of Q^T for S^T = K Q^T.
    short8 aq[4][2];
    for (int mi = 0; mi < 4; mi++)
        for (int ks = 0; ks < 2; ks++)
            aq[mi][ks] = *(const short8*)(Q + base + (size_t)(q0 + mi * 16 + l16) * E_ + ks * 32 + quad * 8);

    floatx4 o[4][4];
    const floatx4 fz = {0.f, 0.f, 0.f, 0.f};
    for (int mi = 0; mi < 4; mi++)
        for (int nd = 0; nd < 4; nd++) o[mi][nd] = fz;

    // K staging: thread t stages key srow = t>>2 into permuted LDS row:
    // key k -> row (k&32) + ((k>>2)&1)*16 + ((k>>3)&3)*4 + (k&3)
    const int srow = t >> 2, sseg = (t & 3) * 16;
    const int prow = (srow & 32) + (((srow >> 2) & 1) << 4)
                   + (((srow >> 3) & 3) << 2) + (srow & 3);
    const u16* Ksrc = Kk + base + (size_t)(key_base + srow) * E_ + sseg;
    u16* kdst = &k_lds[prow * LK + sseg];

    // V staging (fused transpose): read V[key=srow][d=sseg..sseg+16) coalesced,
    // write 16 b16 elems transposed into v_lds[d][key].
    const u16* Vsrc = V + base + (size_t)(key_base + srow) * E_ + sseg;

    for (int kt = 0; kt < KCHUNK / 64; kt++) {
        __syncthreads();
        const u16* kg = Ksrc + (size_t)(kt * 64) * E_;
        const u16* vg = Vsrc + (size_t)(kt * 64) * E_;
        intx4 kv0 = *(const intx4*)(kg);
        intx4 kv1 = *(const intx4*)(kg + 8);
        intx4 vv0 = *(const intx4*)(vg);
        intx4 vv1 = *(const intx4*)(vg + 8);
        *(intx4*)(kdst)     = kv0;
        *(intx4*)(kdst + 8) = kv1;
        const u16* v0p = (const u16*)&vv0;
        const u16* v1p = (const u16*)&vv1;
        for (int i = 0; i < 8; i++) {
            v_lds[(sseg + i) * LV + srow]     = v0p[i];
            v_lds[(sseg + 8 + i) * LV + srow] = v1p[i];
        }
        __syncthreads();

        for (int g = 0; g < 2; g++) {   // 32-key group
            short8 ka[2][2];
            for (int tp = 0; tp < 2; tp++)
                for (int ks = 0; ks < 2; ks++)
                    ka[tp][ks] = *(const short8*)&k_lds[(g * 32 + tp * 16 + l16) * LK + ks * 32 + quad * 8];
            short8 bv[4];
            for (int nd = 0; nd < 4; nd++)
                bv[nd] = *(const short8*)&v_lds[(nd * 16 + l16) * LV + g * 32 + quad * 8];

            for (int mi = 0; mi < 4; mi++) {
                floatx4 c0 = __builtin_amdgcn_mfma_f32_16x16x32_bf16(ka[0][0], aq[mi][0], fz, 0, 0, 0);
                c0 = __builtin_amdgcn_mfma_f32_16x16x32_bf16(ka[0][1], aq[mi][1], c0, 0, 0, 0);
                floatx4 c1 = __builtin_amdgcn_mfma_f32_16x16x32_bf16(ka[1][0], aq[mi][0], fz, 0, 0, 0);
                c1 = __builtin_amdgcn_mfma_f32_16x16x32_bf16(ka[1][1], aq[mi][1], c1, 0, 0, 0);
                union { short4v h[2]; short8 s8; } sf;
                sf.h[0] = relu_pack(c0);    // keys quad*8 + 0..3
                sf.h[1] = relu_pack(c1);    // keys quad*8 + 4..7
                for (int nd = 0; nd < 4; nd++)
                    o[mi][nd] = __builtin_amdgcn_mfma_f32_16x16x32_bf16(sf.s8, bv[nd], o[mi][nd], 0, 0, 0);
            }
        }
    }

    for (int mi = 0; mi < 4; mi++)
        for (int nd = 0; nd < 4; nd++)
            for (int r = 0; r < 4; r++)
                Oa[(size_t)(b * N_ + q0 + mi * 16 + quad * 4 + r) * E_ + h * HD_ + nd * 16 + l16] =
                    f2bf(o[mi][nd][r]);
}

// ---------------------------------------------------------------------------
// LayerNorm over E=1024 of (P0+P1) + gate by u, emit bf16. 1 block/row.
// ---------------------------------------------------------------------------
__launch_bounds__(256, 4)
__global__ void ln_gate(const u16* __restrict__ P0, const u16* __restrict__ P1,
                        const u16* __restrict__ U,
                        const float* __restrict__ G, const float* __restrict__ Bb,
                        u16* __restrict__ Out)
{
    const int row = blockIdx.x;
    const int t = threadIdx.x;
    const size_t idx = (size_t)row * E_ + t * 4;
    const short4v a0 = *(const short4v*)(P0 + idx);
    const short4v a1 = *(const short4v*)(P1 + idx);
    floatx4 v;
    for (int i = 0; i < 4; i++)
        v[i] = bf2f((u16)a0[i]) + bf2f((u16)a1[i]);
    float s  = v[0] + v[1] + v[2] + v[3];
    float ss = v[0] * v[0] + v[1] * v[1] + v[2] * v[2] + v[3] * v[3];
    for (int off = 32; off; off >>= 1) {
        s  += __shfl_down(s, off, 64);
        ss += __shfl_down(ss, off, 64);
    }
    __shared__ float red[8];
    const int wave = t >> 6, lane = t & 63;
    if (lane == 0) { red[wave] = s; red[4 + wave] = ss; }
    __syncthreads();
    const float S  = red[0] + red[1] + red[2] + red[3];
    const float SS = red[4] + red[5] + red[6] + red[7];
    const float mu  = S * (1.f / E_);
    const float var = SS * (1.f / E_) - mu * mu;
    const float rstd = rsqrtf(var + 1e-5f);

    short4v outv;
    for (int i = 0; i < 4; i++) {
        const int e = t * 4 + i;
        float y = (v[i] - mu) * rstd * G[e] + Bb[e];
        y *= bf2f(U[idx + i]);
        outv[i] = (short)f2bf(y);
    }
    *(short4v*)(Out + idx) = outv;
}

// ---------------------------------------------------------------------------
extern "C" void kernel_launch(void* const* d_in, const int* in_sizes, int n_in,
                              void* d_out, int out_size, void* d_ws, size_t ws_size,
                              hipStream_t stream)
{
    const float* x   = (const float*)d_in[0];
    const float* Wq  = (const float*)d_in[1];
    const float* bq  = (const float*)d_in[2];
    const float* Wk  = (const float*)d_in[3];
    const float* bk  = (const float*)d_in[4];
    const float* Wv  = (const float*)d_in[5];
    const float* bv  = (const float*)d_in[6];
    const float* Wu  = (const float*)d_in[7];
    const float* bu  = (const float*)d_in[8];
    const float* Wo  = (const float*)d_in[9];
    const float* bo  = (const float*)d_in[10];
    const float* lng = (const float*)d_in[11];
    const float* lnb = (const float*)d_in[12];

    char* ws = (char*)d_ws;
    u16*  qw  = (u16*)(ws);                      // 8 MB (q row-major, pre-scaled 1/8)
    u16*  kw  = (u16*)(ws + 8388608);            // 8 MB (K row-major)
    u16*  vw  = (u16*)(ws + 16777216);           // 8 MB (V row-major)
    u16*  uw  = (u16*)(ws + 25165824);           // 8 MB (u row-major)
    u16*  p0  = (u16*)(ws + 33554432);           // 8 MB bf16 attn partial z=0
    u16*  p1  = (u16*)(ws + 41943040);           // 8 MB bf16 attn partial z=1
    u16*  xb  = (u16*)(ws + 50331648);           // 8 MB x->bf16
    u16*  wbq = (u16*)(ws + 58720256);           // 2 MB each, bf16 weights
    u16*  wbk = (u16*)(ws + 60817408);
    u16*  wbv = (u16*)(ws + 62914560);
    u16*  wbu = (u16*)(ws + 65011712);
    u16*  wbo = (u16*)(ws + 67108864);
    u16*  gw  = (u16*)(ws);                      // reuses q buffer after attn

    float* out = (float*)d_out;

    const dim3 blk(256, 1, 1);

    // dtype prep (x + 5 weights, one launch)
    cvt6<<<dim3(M_TOT * E_ / 2048, 1, 6), blk, 0, stream>>>(
        x, Wq, Wk, Wv, Wu, Wo, xb, wbq, wbk, wbv, wbu, wbo);
    // q,k,v,u projections (silu on v,u; q scaled 1/8)
    gemm4<u16><<<dim3(8, 32, 4), blk, 0, stream>>>(xb, wbq, wbk, wbv, wbu,
                                                   bq, bk, bv, bu,
                                                   qw, kw, vw, uw, 0xC, 0x1, E_);
    // attention v6: 256q blocks, key-split x2, x32 PV
    attn<<<dim3(N_ / 256, B_ * H_, KSPLIT), blk, 0, stream>>>(qw, kw, vw, p0, p1);
    // layernorm(sum of 2 partials) + gate
    ln_gate<<<dim3(M_TOT, 1, 1), blk, 0, stream>>>(p0, p1, uw, lng, lnb, gw);
    // output projection -> fp32 d_out: 64x128 tiles, 512 blocks (2/CU)
    gemm_out<<<dim3(E_ / 128, M_TOT / 64, 1), blk, 0, stream>>>(gw, wbo, bo, out, E_);
}

// Round 2
// 210.086 us; speedup vs baseline: 1.0756x; 1.0140x over previous
//
#include <hip/hip_runtime.h>
#include <stdint.h>

typedef unsigned short u16;
typedef __attribute__((ext_vector_type(8))) short short8;
typedef __attribute__((ext_vector_type(4))) short short4v;
typedef __attribute__((ext_vector_type(4))) float floatx4;
typedef __attribute__((ext_vector_type(4))) int intx4;

#define B_ 2
#define N_ 2048
#define E_ 1024
#define H_ 16
#define HD_ 64
#define M_TOT (B_ * N_)   // 4096

__device__ __forceinline__ float bf2f(u16 h) {
    union { unsigned u; float f; } c; c.u = ((unsigned)h) << 16; return c.f;
}
__device__ __forceinline__ u16 f2bf(float f) {
    union { float f; unsigned u; } c; c.f = f;
    unsigned r = c.u + 0x7FFFu + ((c.u >> 16) & 1u);
    return (u16)(r >> 16);
}
__device__ __forceinline__ float silu_f(float x) { return x / (1.f + __expf(-x)); }

// Direct global->LDS 16B async copy. LDS dest = wave-uniform base + lane*16.
__device__ __forceinline__ void gll16(const void* g, void* l) {
    __builtin_amdgcn_global_load_lds(
        (const __attribute__((address_space(1))) void*)g,
        (__attribute__((address_space(3))) void*)l,
        16, 0, 0);
}

// relu(+pack) four fp32 -> 4 bf16 (round-half-up), order preserved.
__device__ __forceinline__ short4v relu_pack(floatx4 s) {
    union { float f; unsigned u; } c0, c1, c2, c3;
    c0.f = fmaxf(s[0], 0.f); c1.f = fmaxf(s[1], 0.f);
    c2.f = fmaxf(s[2], 0.f); c3.f = fmaxf(s[3], 0.f);
    unsigned lo = __builtin_amdgcn_perm(c1.u + 0x8000u, c0.u + 0x8000u, 0x07060302);
    unsigned hi = __builtin_amdgcn_perm(c3.u + 0x8000u, c2.u + 0x8000u, 0x07060302);
    union { unsigned v[2]; short4v s4; } r; r.v[0] = lo; r.v[1] = hi;
    return r.s4;
}

// ---------------------------------------------------------------------------
// fp32 -> bf16 for x (z=0, 2048 blocks) and 5 weights (z=1..5, 512 blocks).
// ---------------------------------------------------------------------------
__launch_bounds__(256, 4)
__global__ void cvt6(const float* __restrict__ s0, const float* __restrict__ s1,
                     const float* __restrict__ s2, const float* __restrict__ s3,
                     const float* __restrict__ s4, const float* __restrict__ s5,
                     u16* __restrict__ d0, u16* __restrict__ d1,
                     u16* __restrict__ d2, u16* __restrict__ d3,
                     u16* __restrict__ d4, u16* __restrict__ d5)
{
    const int z = blockIdx.z;
    if (z > 0 && blockIdx.x >= E_ * E_ / 2048) return;
    const float* src = (z == 0) ? s0 : (z == 1) ? s1 : (z == 2) ? s2
                     : (z == 3) ? s3 : (z == 4) ? s4 : s5;
    u16* dst         = (z == 0) ? d0 : (z == 1) ? d1 : (z == 2) ? d2
                     : (z == 3) ? d3 : (z == 4) ? d4 : d5;
    const int i = (blockIdx.x * 256 + threadIdx.x) * 8;
    floatx4 a = *(const floatx4*)(src + i);
    floatx4 b = *(const floatx4*)(src + i + 4);
    union { u16 h[8]; intx4 v; } o;
    o.h[0] = f2bf(a[0]); o.h[1] = f2bf(a[1]); o.h[2] = f2bf(a[2]); o.h[3] = f2bf(a[3]);
    o.h[4] = f2bf(b[0]); o.h[5] = f2bf(b[1]); o.h[6] = f2bf(b[2]); o.h[7] = f2bf(b[3]);
    *(intx4*)(dst + i) = o.v;
}

// ---------------------------------------------------------------------------
// Projection GEMM, 256x256 8-phase schedule (m201 structure, T2+T3+T4+T5):
// C[4096,1024] = act( A @ W^T + bias ) [*osc], z selects weight/out.
// 512 thr = 8 waves (2 M x 4 N), per-wave 128x64 out, BK=64, 128 KiB LDS
// (2 K-tile dbuf). LDS layout: per K-32 plane [128 rows][32 cols] bf16 with
// col-byte ^= ((row>>3)&1)<<5 swizzle (pre-swizzled global src + swizzled
// ds_read -> conflict-free b128 across 32 banks).
// Per K-tile 4 phases: {ds-read frag subtile | stage 1 half-tile | barrier |
// setprio(1) 16 MFMA setprio(0) | barrier}; vmcnt(4) ONLY at tile boundary.
// Staging schedule per tile t: P0/P1: (t+1).B halves (other buf, free since
// t-1.P2); P2/P3: (t+2).A halves (own buf, A last read at t.P1). vmcnt(4)
// at boundary leaves exactly the 4 newest loads ((t+2).A) in flight and
// forces all of (t+1)'s halves landed.
// ---------------------------------------------------------------------------
#define NTILES (E_ / 64)    // 16 K-tiles

#define LDA_FRAGS(mlo, BUF)                                                        \
    _Pragma("unroll")                                                              \
    for (int mi = 0; mi < 4; mi++) {                                               \
        af[(mlo) + mi][0] = *(const short8*)&lds[(BUF)*16384 + raA + ((mlo)+mi)*512];        \
        af[(mlo) + mi][1] = *(const short8*)&lds[(BUF)*16384 + raA + 4096 + ((mlo)+mi)*512]; \
    }

#define LDB_FRAGS(blo, BUF)                                                        \
    _Pragma("unroll")                                                              \
    for (int bn = 0; bn < 2; bn++) {                                               \
        bfr[bn][0] = *(const short8*)&lds[32768 + (BUF)*16384 + raB + ((blo)+bn)*512];        \
        bfr[bn][1] = *(const short8*)&lds[32768 + (BUF)*16384 + raB + 4096 + ((blo)+bn)*512]; \
    }

#define MFMAQ(mlo, blo)                                                            \
    _Pragma("unroll")                                                              \
    for (int mi = 0; mi < 4; mi++)                                                 \
        _Pragma("unroll")                                                          \
        for (int bn = 0; bn < 2; bn++) {                                           \
            acc[(mlo)+mi][(blo)+bn] = __builtin_amdgcn_mfma_f32_16x16x32_bf16(     \
                af[(mlo)+mi][0], bfr[bn][0], acc[(mlo)+mi][(blo)+bn], 0, 0, 0);    \
            acc[(mlo)+mi][(blo)+bn] = __builtin_amdgcn_mfma_f32_16x16x32_bf16(     \
                af[(mlo)+mi][1], bfr[bn][1], acc[(mlo)+mi][(blo)+bn], 0, 0, 0);    \
        }

#define STAGE_AH(t2, h, BUFX)                                                      \
    if ((t2) < NTILES) {                                                           \
        gll16(As + (size_t)(h)*128*E_ + (t2)*64,      &lds[(BUFX)*16384 + (h)*8192 + wid*512]);        \
        gll16(As + (size_t)(h)*128*E_ + (t2)*64 + 32, &lds[(BUFX)*16384 + (h)*8192 + 4096 + wid*512]); \
    }

#define STAGE_BH(t1, h, BUFX)                                                      \
    if ((t1) < NTILES) {                                                           \
        gll16(Bs + (size_t)(h)*128*E_ + (t1)*64,      &lds[32768 + (BUFX)*16384 + (h)*8192 + wid*512]);        \
        gll16(Bs + (size_t)(h)*128*E_ + (t1)*64 + 32, &lds[32768 + (BUFX)*16384 + (h)*8192 + 4096 + wid*512]); \
    }

#define TILE(t, BUF) {                                                             \
    LDA_FRAGS(0, BUF); LDB_FRAGS(0, BUF);                                          \
    STAGE_BH((t)+1, 0, (BUF)^1);                                                   \
    __builtin_amdgcn_s_barrier();                                                  \
    __builtin_amdgcn_s_setprio(1); MFMAQ(0, 0); __builtin_amdgcn_s_setprio(0);     \
    __builtin_amdgcn_s_barrier();                                                  \
    LDA_FRAGS(4, BUF);                                                             \
    STAGE_BH((t)+1, 1, (BUF)^1);                                                   \
    __builtin_amdgcn_s_barrier();                                                  \
    __builtin_amdgcn_s_setprio(1); MFMAQ(4, 0); __builtin_amdgcn_s_setprio(0);     \
    __builtin_amdgcn_s_barrier();                                                  \
    LDB_FRAGS(2, BUF);                                                             \
    STAGE_AH((t)+2, 0, BUF);                                                       \
    __builtin_amdgcn_s_barrier();                                                  \
    __builtin_amdgcn_s_setprio(1); MFMAQ(4, 2); __builtin_amdgcn_s_setprio(0);     \
    __builtin_amdgcn_s_barrier();                                                  \
    STAGE_AH((t)+2, 1, BUF);                                                       \
    __builtin_amdgcn_s_barrier();                                                  \
    __builtin_amdgcn_s_setprio(1); MFMAQ(0, 2); __builtin_amdgcn_s_setprio(0);     \
    asm volatile("s_waitcnt vmcnt(4)" ::: "memory");                               \
    __builtin_amdgcn_s_barrier();                                                  \
}

__launch_bounds__(512, 2)
__global__ void gemm8p(const u16* __restrict__ A,
                       const u16* __restrict__ W0, const u16* __restrict__ W1,
                       const u16* __restrict__ W2, const u16* __restrict__ W3,
                       const float* __restrict__ bi0, const float* __restrict__ bi1,
                       const float* __restrict__ bi2, const float* __restrict__ bi3,
                       u16* __restrict__ O0, u16* __restrict__ O1,
                       u16* __restrict__ O2, u16* __restrict__ O3,
                       int actmask, int scalemask)
{
    __shared__ u16 lds[65536];   // 128 KiB: A 2buf x 2half x [2 planes][128][32]; B at +32768

    const int z = blockIdx.z;
    const u16* Wp   = (z == 0) ? W0 : (z == 1) ? W1 : (z == 2) ? W2 : W3;
    const float* Bi = (z == 0) ? bi0 : (z == 1) ? bi1 : (z == 2) ? bi2 : bi3;
    u16* Out        = (z == 0) ? O0 : (z == 1) ? O1 : (z == 2) ? O2 : O3;
    const bool act = (actmask >> z) & 1;
    const float osc = ((scalemask >> z) & 1) ? 0.125f : 1.0f;

    const int tid = threadIdx.x;
    const int wid = tid >> 6, lane = tid & 63, quad = lane >> 4, l16 = lane & 15;
    const int wm = wid >> 2, wn = wid & 3;     // 2 M-waves x 4 N-waves
    const int m0 = blockIdx.y * 256;
    const int n0 = blockIdx.x * 256;

    // read-side swizzled bases (elements): plane layout [128][32], swizzle
    // col_elem ^= ((row>>3)&1)*16
    const int swz = ((l16 >> 3) & 1) * 16;
    const int raA = wm * 8192 + l16 * 32 + ((quad * 8) ^ swz);
    const int raB = (wn >> 1) * 8192 + ((wn & 1) * 64 + l16) * 32 + ((quad * 8) ^ swz);

    // staging source: thread tid covers plane elems [tid*8, tid*8+8) = row
    // tid>>2, linear cols (tid&3)*8; inverse-swizzled global col:
    const int srow_s = tid >> 2;
    const int sce = ((tid & 3) * 8) ^ (((tid >> 5) & 1) * 16);
    const u16* As = A  + (size_t)(m0 + srow_s) * E_ + sce;
    const u16* Bs = Wp + (size_t)(n0 + srow_s) * E_ + sce;

    floatx4 acc[8][4];
    const floatx4 fz = {0.f, 0.f, 0.f, 0.f};
#pragma unroll
    for (int mi = 0; mi < 8; mi++)
#pragma unroll
        for (int bn = 0; bn < 4; bn++) acc[mi][bn] = fz;

    short8 af[8][2], bfr[2][2];

    // prologue: t0 A+B (8 planes), t1 A (4 planes); vmcnt(4) -> t0 landed,
    // t1.A in flight (steady-state invariant entering tile 0).
    gll16(As,                  &lds[0     + wid*512]);
    gll16(As + 32,             &lds[4096  + wid*512]);
    gll16(As + 128*E_,         &lds[8192  + wid*512]);
    gll16(As + 128*E_ + 32,    &lds[12288 + wid*512]);
    gll16(Bs,                  &lds[32768 +  0    + wid*512]);
    gll16(Bs + 32,             &lds[32768 + 4096  + wid*512]);
    gll16(Bs + 128*E_,         &lds[32768 + 8192  + wid*512]);
    gll16(Bs + 128*E_ + 32,    &lds[32768 + 12288 + wid*512]);
    gll16(As + 64,             &lds[16384 +  0    + wid*512]);
    gll16(As + 96,             &lds[16384 + 4096  + wid*512]);
    gll16(As + 128*E_ + 64,    &lds[16384 + 8192  + wid*512]);
    gll16(As + 128*E_ + 96,    &lds[16384 + 12288 + wid*512]);
    asm volatile("s_waitcnt vmcnt(4)" ::: "memory");
    __builtin_amdgcn_s_barrier();

    for (int tt = 0; tt < NTILES; tt += 2) {
        TILE(tt, 0);
        TILE(tt + 1, 1);
    }

    float bias_v[4];
#pragma unroll
    for (int bn = 0; bn < 4; bn++) bias_v[bn] = Bi[n0 + wn * 64 + bn * 16 + l16];

#pragma unroll
    for (int mi = 0; mi < 8; mi++) {
        const int row = m0 + wm * 128 + mi * 16 + quad * 4;
#pragma unroll
        for (int bn = 0; bn < 4; bn++) {
            const int col = n0 + wn * 64 + bn * 16 + l16;
#pragma unroll
            for (int r = 0; r < 4; r++) {
                float v = acc[mi][bn][r] + bias_v[bn];
                if (act) v = silu_f(v);
                v *= osc;
                Out[(size_t)(row + r) * E_ + col] = f2bf(v);
            }
        }
    }
}

// ---------------------------------------------------------------------------
// Output projection GEMM: 64x128 tile (BMxBN), grid (E/128, M/64) = 512 blocks
// -> 2 blocks/CU residency (128x128 at grid=256 was 1 block/CU and
// latency-bound at 50 us). Waves split N. fp32 out + bias, no act.
// ---------------------------------------------------------------------------
__launch_bounds__(256, 2)
__global__ void gemm_out(const u16* __restrict__ A, const u16* __restrict__ W,
                         const float* __restrict__ Bi, float* __restrict__ Out,
                         int K)
{
    __shared__ u16 a_lds[64 * 32];    // 4 KB
    __shared__ u16 b_lds[128 * 32];   // 8 KB

    const int t    = threadIdx.x;
    const int wave = t >> 6, lane = t & 63, quad = lane >> 4, l16 = lane & 15;
    const int m0 = blockIdx.y * 64;
    const int n0 = blockIdx.x * 128;

    floatx4 acc[4][2];
    const floatx4 fz = {0.f, 0.f, 0.f, 0.f};
    for (int i = 0; i < 4; i++)
        for (int j = 0; j < 2; j++) acc[i][j] = fz;

    const int ar = t >> 2;
    const int ac = (t & 3) * 8;
    const u16* Ag0 = A + (size_t)(m0 + ar) * K + ac;
    const u16* Bg0 = W + (size_t)(n0 + ar) * K + ac;
    const u16* Bg1 = W + (size_t)(n0 + 64 + ar) * K + ac;
    u16* al0 = a_lds + wave * 512;
    u16* bl0 = b_lds + wave * 512;
    u16* bl1 = b_lds + 2048 + wave * 512;

    for (int k0 = 0; k0 < K; k0 += 32) {
        __syncthreads();
        gll16(Ag0 + k0, al0);
        gll16(Bg0 + k0, bl0);
        gll16(Bg1 + k0, bl1);
        __syncthreads();

        short8 af[4], bfr[2];
        for (int i = 0; i < 4; i++)
            af[i]  = *(const short8*)&a_lds[(i * 16 + l16) * 32 + quad * 8];
        for (int j = 0; j < 2; j++)
            bfr[j] = *(const short8*)&b_lds[(wave * 32 + j * 16 + l16) * 32 + quad * 8];
        for (int i = 0; i < 4; i++)
            for (int j = 0; j < 2; j++)
                acc[i][j] = __builtin_amdgcn_mfma_f32_16x16x32_bf16(af[i], bfr[j], acc[i][j], 0, 0, 0);
    }

    float bias_v[2];
    for (int j = 0; j < 2; j++) bias_v[j] = Bi[n0 + wave * 32 + j * 16 + l16];

    for (int i = 0; i < 4; i++) {
        const int row = m0 + i * 16 + quad * 4;
        for (int j = 0; j < 2; j++) {
            const int col = n0 + wave * 32 + j * 16 + l16;
            for (int r = 0; r < 4; r++)
                Out[(size_t)(row + r) * E_ + col] = acc[i][j][r] + bias_v[j];
        }
    }
}

// ---------------------------------------------------------------------------
// Attention v6: O = relu(Q K^T) @ V, Q pre-scaled 1/8. KSPLIT=2. vtrans fused
// into staging (V read row-major coalesced, transposed into padded [64][72]
// LDS). QK: S^T = K Q^T (x32), K rows ROW-PERMUTED (LK=72) so two 16-key
// C-tiles relu_pack in-register into the exact x32 PV A-frag.
// Block: 256 q (4 waves x 64 q) x (b,h) x key-chunk z, 64-key tiles.
// ---------------------------------------------------------------------------
#define LK 72
#define LV 72
#define KSPLIT 2
#define KCHUNK (N_ / KSPLIT)    // 1024 keys per z

__launch_bounds__(256, 2)
__global__ void attn(const u16* __restrict__ Q, const u16* __restrict__ Kk,
                     const u16* __restrict__ V,
                     u16* __restrict__ P0, u16* __restrict__ P1)
{
    __shared__ u16 k_lds[64 * LK];    // row-permuted [keyslot][d]
    __shared__ u16 v_lds[64 * LV];    // [d][key], padded stride

    const int bh = blockIdx.y;
    const int b = bh >> 4, h = bh & 15;
    const int z = blockIdx.z;
    u16* __restrict__ Oa = (z == 0) ? P0 : P1;
    const int key_base = z * KCHUNK;

    const int t = threadIdx.x;
    const int wave = t >> 6, lane = t & 63, quad = lane >> 4, l16 = lane & 15;
    const int q0 = blockIdx.x * 256 + wave * 64;
    const size_t base = (size_t)b * N_ * E_ + h * HD_;

    short8 aq[4][2];
    for (int mi = 0; mi < 4; mi++)
        for (int ks = 0; ks < 2; ks++)
            aq[mi][ks] = *(const short8*)(Q + base + (size_t)(q0 + mi * 16 + l16) * E_ + ks * 32 + quad * 8);

    floatx4 o[4][4];
    const floatx4 fz = {0.f, 0.f, 0.f, 0.f};
    for (int mi = 0; mi < 4; mi++)
        for (int nd = 0; nd < 4; nd++) o[mi][nd] = fz;

    const int srow = t >> 2, sseg = (t & 3) * 16;
    const int prow = (srow & 32) + (((srow >> 2) & 1) << 4)
                   + (((srow >> 3) & 3) << 2) + (srow & 3);
    const u16* Ksrc = Kk + base + (size_t)(key_base + srow) * E_ + sseg;
    u16* kdst = &k_lds[prow * LK + sseg];
    const u16* Vsrc = V + base + (size_t)(key_base + srow) * E_ + sseg;

    for (int kt = 0; kt < KCHUNK / 64; kt++) {
        __syncthreads();
        const u16* kg = Ksrc + (size_t)(kt * 64) * E_;
        const u16* vg = Vsrc + (size_t)(kt * 64) * E_;
        intx4 kv0 = *(const intx4*)(kg);
        intx4 kv1 = *(const intx4*)(kg + 8);
        intx4 vv0 = *(const intx4*)(vg);
        intx4 vv1 = *(const intx4*)(vg + 8);
        *(intx4*)(kdst)     = kv0;
        *(intx4*)(kdst + 8) = kv1;
        const u16* v0p = (const u16*)&vv0;
        const u16* v1p = (const u16*)&vv1;
        for (int i = 0; i < 8; i++) {
            v_lds[(sseg + i) * LV + srow]     = v0p[i];
            v_lds[(sseg + 8 + i) * LV + srow] = v1p[i];
        }
        __syncthreads();

        for (int g = 0; g < 2; g++) {   // 32-key group
            short8 ka[2][2];
            for (int tp = 0; tp < 2; tp++)
                for (int ks = 0; ks < 2; ks++)
                    ka[tp][ks] = *(const short8*)&k_lds[(g * 32 + tp * 16 + l16) * LK + ks * 32 + quad * 8];
            short8 bv[4];
            for (int nd = 0; nd < 4; nd++)
                bv[nd] = *(const short8*)&v_lds[(nd * 16 + l16) * LV + g * 32 + quad * 8];

            for (int mi = 0; mi < 4; mi++) {
                floatx4 c0 = __builtin_amdgcn_mfma_f32_16x16x32_bf16(ka[0][0], aq[mi][0], fz, 0, 0, 0);
                c0 = __builtin_amdgcn_mfma_f32_16x16x32_bf16(ka[0][1], aq[mi][1], c0, 0, 0, 0);
                floatx4 c1 = __builtin_amdgcn_mfma_f32_16x16x32_bf16(ka[1][0], aq[mi][0], fz, 0, 0, 0);
                c1 = __builtin_amdgcn_mfma_f32_16x16x32_bf16(ka[1][1], aq[mi][1], c1, 0, 0, 0);
                union { short4v h[2]; short8 s8; } sf;
                sf.h[0] = relu_pack(c0);
                sf.h[1] = relu_pack(c1);
                for (int nd = 0; nd < 4; nd++)
                    o[mi][nd] = __builtin_amdgcn_mfma_f32_16x16x32_bf16(sf.s8, bv[nd], o[mi][nd], 0, 0, 0);
            }
        }
    }

    for (int mi = 0; mi < 4; mi++)
        for (int nd = 0; nd < 4; nd++)
            for (int r = 0; r < 4; r++)
                Oa[(size_t)(b * N_ + q0 + mi * 16 + quad * 4 + r) * E_ + h * HD_ + nd * 16 + l16] =
                    f2bf(o[mi][nd][r]);
}

// ---------------------------------------------------------------------------
// LayerNorm over E=1024 of (P0+P1) + gate by u, emit bf16. 1 block/row.
// ---------------------------------------------------------------------------
__launch_bounds__(256, 4)
__global__ void ln_gate(const u16* __restrict__ P0, const u16* __restrict__ P1,
                        const u16* __restrict__ U,
                        const float* __restrict__ G, const float* __restrict__ Bb,
                        u16* __restrict__ Out)
{
    const int row = blockIdx.x;
    const int t = threadIdx.x;
    const size_t idx = (size_t)row * E_ + t * 4;
    const short4v a0 = *(const short4v*)(P0 + idx);
    const short4v a1 = *(const short4v*)(P1 + idx);
    floatx4 v;
    for (int i = 0; i < 4; i++)
        v[i] = bf2f((u16)a0[i]) + bf2f((u16)a1[i]);
    float s  = v[0] + v[1] + v[2] + v[3];
    float ss = v[0] * v[0] + v[1] * v[1] + v[2] * v[2] + v[3] * v[3];
    for (int off = 32; off; off >>= 1) {
        s  += __shfl_down(s, off, 64);
        ss += __shfl_down(ss, off, 64);
    }
    __shared__ float red[8];
    const int wave = t >> 6, lane = t & 63;
    if (lane == 0) { red[wave] = s; red[4 + wave] = ss; }
    __syncthreads();
    const float S  = red[0] + red[1] + red[2] + red[3];
    const float SS = red[4] + red[5] + red[6] + red[7];
    const float mu  = S * (1.f / E_);
    const float var = SS * (1.f / E_) - mu * mu;
    const float rstd = rsqrtf(var + 1e-5f);

    short4v outv;
    for (int i = 0; i < 4; i++) {
        const int e = t * 4 + i;
        float y = (v[i] - mu) * rstd * G[e] + Bb[e];
        y *= bf2f(U[idx + i]);
        outv[i] = (short)f2bf(y);
    }
    *(short4v*)(Out + idx) = outv;
}

// ---------------------------------------------------------------------------
extern "C" void kernel_launch(void* const* d_in, const int* in_sizes, int n_in,
                              void* d_out, int out_size, void* d_ws, size_t ws_size,
                              hipStream_t stream)
{
    const float* x   = (const float*)d_in[0];
    const float* Wq  = (const float*)d_in[1];
    const float* bq  = (const float*)d_in[2];
    const float* Wk  = (const float*)d_in[3];
    const float* bk  = (const float*)d_in[4];
    const float* Wv  = (const float*)d_in[5];
    const float* bv  = (const float*)d_in[6];
    const float* Wu  = (const float*)d_in[7];
    const float* bu  = (const float*)d_in[8];
    const float* Wo  = (const float*)d_in[9];
    const float* bo  = (const float*)d_in[10];
    const float* lng = (const float*)d_in[11];
    const float* lnb = (const float*)d_in[12];

    char* ws = (char*)d_ws;
    u16*  qw  = (u16*)(ws);                      // 8 MB (q row-major, pre-scaled 1/8)
    u16*  kw  = (u16*)(ws + 8388608);            // 8 MB (K row-major)
    u16*  vw  = (u16*)(ws + 16777216);           // 8 MB (V row-major)
    u16*  uw  = (u16*)(ws + 25165824);           // 8 MB (u row-major)
    u16*  p0  = (u16*)(ws + 33554432);           // 8 MB bf16 attn partial z=0
    u16*  p1  = (u16*)(ws + 41943040);           // 8 MB bf16 attn partial z=1
    u16*  xb  = (u16*)(ws + 50331648);           // 8 MB x->bf16
    u16*  wbq = (u16*)(ws + 58720256);           // 2 MB each, bf16 weights
    u16*  wbk = (u16*)(ws + 60817408);
    u16*  wbv = (u16*)(ws + 62914560);
    u16*  wbu = (u16*)(ws + 65011712);
    u16*  wbo = (u16*)(ws + 67108864);
    u16*  gw  = (u16*)(ws);                      // reuses q buffer after attn

    float* out = (float*)d_out;

    // dtype prep (x + 5 weights, one launch)
    cvt6<<<dim3(M_TOT * E_ / 2048, 1, 6), dim3(256, 1, 1), 0, stream>>>(
        x, Wq, Wk, Wv, Wu, Wo, xb, wbq, wbk, wbv, wbu, wbo);
    // q,k,v,u projections, 256x256 8-phase (silu on v,u; q scaled 1/8)
    gemm8p<<<dim3(E_ / 256, M_TOT / 256, 4), dim3(512, 1, 1), 0, stream>>>(
        xb, wbq, wbk, wbv, wbu, bq, bk, bv, bu, qw, kw, vw, uw, 0xC, 0x1);
    // attention v6: 256q blocks, key-split x2, x32 PV
    attn<<<dim3(N_ / 256, B_ * H_, KSPLIT), dim3(256, 1, 1), 0, stream>>>(qw, kw, vw, p0, p1);
    // layernorm(sum of 2 partials) + gate
    ln_gate<<<dim3(M_TOT, 1, 1), dim3(256, 1, 1), 0, stream>>>(p0, p1, uw, lng, lnb, gw);
    // output projection -> fp32 d_out: 64x128 tiles, 512 blocks (2/CU)
    gemm_out<<<dim3(E_ / 128, M_TOT / 64, 1), dim3(256, 1, 1), 0, stream>>>(gw, wbo, bo, out, E_);
}

// Round 3
// 207.611 us; speedup vs baseline: 1.0884x; 1.0119x over previous
//
#include <hip/hip_runtime.h>
#include <stdint.h>

typedef unsigned short u16;
typedef __attribute__((ext_vector_type(8))) short short8;
typedef __attribute__((ext_vector_type(4))) short short4v;
typedef __attribute__((ext_vector_type(4))) float floatx4;
typedef __attribute__((ext_vector_type(4))) int intx4;

#define B_ 2
#define N_ 2048
#define E_ 1024
#define H_ 16
#define HD_ 64
#define M_TOT (B_ * N_)   // 4096

__device__ __forceinline__ float bf2f(u16 h) {
    union { unsigned u; float f; } c; c.u = ((unsigned)h) << 16; return c.f;
}
__device__ __forceinline__ u16 f2bf(float f) {
    union { float f; unsigned u; } c; c.f = f;
    unsigned r = c.u + 0x7FFFu + ((c.u >> 16) & 1u);
    return (u16)(r >> 16);
}
__device__ __forceinline__ float silu_f(float x) { return x / (1.f + __expf(-x)); }

// Direct global->LDS 16B async copy. LDS dest = wave-uniform base + lane*16.
__device__ __forceinline__ void gll16(const void* g, void* l) {
    __builtin_amdgcn_global_load_lds(
        (const __attribute__((address_space(1))) void*)g,
        (__attribute__((address_space(3))) void*)l,
        16, 0, 0);
}

// relu(+pack) four fp32 -> 4 bf16 (round-half-up), order preserved.
__device__ __forceinline__ short4v relu_pack(floatx4 s) {
    union { float f; unsigned u; } c0, c1, c2, c3;
    c0.f = fmaxf(s[0], 0.f); c1.f = fmaxf(s[1], 0.f);
    c2.f = fmaxf(s[2], 0.f); c3.f = fmaxf(s[3], 0.f);
    unsigned lo = __builtin_amdgcn_perm(c1.u + 0x8000u, c0.u + 0x8000u, 0x07060302);
    unsigned hi = __builtin_amdgcn_perm(c3.u + 0x8000u, c2.u + 0x8000u, 0x07060302);
    union { unsigned v[2]; short4v s4; } r; r.v[0] = lo; r.v[1] = hi;
    return r.s4;
}

// ---------------------------------------------------------------------------
// fp32 -> bf16 for x (z=0, 2048 blocks) and 5 weights (z=1..5, 512 blocks).
// ---------------------------------------------------------------------------
__launch_bounds__(256, 4)
__global__ void cvt6(const float* __restrict__ s0, const float* __restrict__ s1,
                     const float* __restrict__ s2, const float* __restrict__ s3,
                     const float* __restrict__ s4, const float* __restrict__ s5,
                     u16* __restrict__ d0, u16* __restrict__ d1,
                     u16* __restrict__ d2, u16* __restrict__ d3,
                     u16* __restrict__ d4, u16* __restrict__ d5)
{
    const int z = blockIdx.z;
    if (z > 0 && blockIdx.x >= E_ * E_ / 2048) return;
    const float* src = (z == 0) ? s0 : (z == 1) ? s1 : (z == 2) ? s2
                     : (z == 3) ? s3 : (z == 4) ? s4 : s5;
    u16* dst         = (z == 0) ? d0 : (z == 1) ? d1 : (z == 2) ? d2
                     : (z == 3) ? d3 : (z == 4) ? d4 : d5;
    const int i = (blockIdx.x * 256 + threadIdx.x) * 8;
    floatx4 a = *(const floatx4*)(src + i);
    floatx4 b = *(const floatx4*)(src + i + 4);
    union { u16 h[8]; intx4 v; } o;
    o.h[0] = f2bf(a[0]); o.h[1] = f2bf(a[1]); o.h[2] = f2bf(a[2]); o.h[3] = f2bf(a[3]);
    o.h[4] = f2bf(b[0]); o.h[5] = f2bf(b[1]); o.h[6] = f2bf(b[2]); o.h[7] = f2bf(b[3]);
    *(intx4*)(dst + i) = o.v;
}

// ---------------------------------------------------------------------------
// Projection GEMM, 256x256 8-phase schedule (m201 structure, T2+T3+T4+T5):
// C[4096,1024] = act( A @ W^T + bias ) [*osc], z selects weight/out.
// UNCHANGED this round (no counters visible yet; will top next round's table).
// ---------------------------------------------------------------------------
#define NTILES (E_ / 64)    // 16 K-tiles

#define LDA_FRAGS(mlo, BUF)                                                        \
    _Pragma("unroll")                                                              \
    for (int mi = 0; mi < 4; mi++) {                                               \
        af[(mlo) + mi][0] = *(const short8*)&lds[(BUF)*16384 + raA + ((mlo)+mi)*512];        \
        af[(mlo) + mi][1] = *(const short8*)&lds[(BUF)*16384 + raA + 4096 + ((mlo)+mi)*512]; \
    }

#define LDB_FRAGS(blo, BUF)                                                        \
    _Pragma("unroll")                                                              \
    for (int bn = 0; bn < 2; bn++) {                                               \
        bfr[bn][0] = *(const short8*)&lds[32768 + (BUF)*16384 + raB + ((blo)+bn)*512];        \
        bfr[bn][1] = *(const short8*)&lds[32768 + (BUF)*16384 + raB + 4096 + ((blo)+bn)*512]; \
    }

#define MFMAQ(mlo, blo)                                                            \
    _Pragma("unroll")                                                              \
    for (int mi = 0; mi < 4; mi++)                                                 \
        _Pragma("unroll")                                                          \
        for (int bn = 0; bn < 2; bn++) {                                           \
            acc[(mlo)+mi][(blo)+bn] = __builtin_amdgcn_mfma_f32_16x16x32_bf16(     \
                af[(mlo)+mi][0], bfr[bn][0], acc[(mlo)+mi][(blo)+bn], 0, 0, 0);    \
            acc[(mlo)+mi][(blo)+bn] = __builtin_amdgcn_mfma_f32_16x16x32_bf16(     \
                af[(mlo)+mi][1], bfr[bn][1], acc[(mlo)+mi][(blo)+bn], 0, 0, 0);    \
        }

#define STAGE_AH(t2, h, BUFX)                                                      \
    if ((t2) < NTILES) {                                                           \
        gll16(As + (size_t)(h)*128*E_ + (t2)*64,      &lds[(BUFX)*16384 + (h)*8192 + wid*512]);        \
        gll16(As + (size_t)(h)*128*E_ + (t2)*64 + 32, &lds[(BUFX)*16384 + (h)*8192 + 4096 + wid*512]); \
    }

#define STAGE_BH(t1, h, BUFX)                                                      \
    if ((t1) < NTILES) {                                                           \
        gll16(Bs + (size_t)(h)*128*E_ + (t1)*64,      &lds[32768 + (BUFX)*16384 + (h)*8192 + wid*512]);        \
        gll16(Bs + (size_t)(h)*128*E_ + (t1)*64 + 32, &lds[32768 + (BUFX)*16384 + (h)*8192 + 4096 + wid*512]); \
    }

#define TILE(t, BUF) {                                                             \
    LDA_FRAGS(0, BUF); LDB_FRAGS(0, BUF);                                          \
    STAGE_BH((t)+1, 0, (BUF)^1);                                                   \
    __builtin_amdgcn_s_barrier();                                                  \
    __builtin_amdgcn_s_setprio(1); MFMAQ(0, 0); __builtin_amdgcn_s_setprio(0);     \
    __builtin_amdgcn_s_barrier();                                                  \
    LDA_FRAGS(4, BUF);                                                             \
    STAGE_BH((t)+1, 1, (BUF)^1);                                                   \
    __builtin_amdgcn_s_barrier();                                                  \
    __builtin_amdgcn_s_setprio(1); MFMAQ(4, 0); __builtin_amdgcn_s_setprio(0);     \
    __builtin_amdgcn_s_barrier();                                                  \
    LDB_FRAGS(2, BUF);                                                             \
    STAGE_AH((t)+2, 0, BUF);                                                       \
    __builtin_amdgcn_s_barrier();                                                  \
    __builtin_amdgcn_s_setprio(1); MFMAQ(4, 2); __builtin_amdgcn_s_setprio(0);     \
    __builtin_amdgcn_s_barrier();                                                  \
    STAGE_AH((t)+2, 1, BUF);                                                       \
    __builtin_amdgcn_s_barrier();                                                  \
    __builtin_amdgcn_s_setprio(1); MFMAQ(0, 2); __builtin_amdgcn_s_setprio(0);     \
    asm volatile("s_waitcnt vmcnt(4)" ::: "memory");                               \
    __builtin_amdgcn_s_barrier();                                                  \
}

__launch_bounds__(512, 2)
__global__ void gemm8p(const u16* __restrict__ A,
                       const u16* __restrict__ W0, const u16* __restrict__ W1,
                       const u16* __restrict__ W2, const u16* __restrict__ W3,
                       const float* __restrict__ bi0, const float* __restrict__ bi1,
                       const float* __restrict__ bi2, const float* __restrict__ bi3,
                       u16* __restrict__ O0, u16* __restrict__ O1,
                       u16* __restrict__ O2, u16* __restrict__ O3,
                       int actmask, int scalemask)
{
    __shared__ u16 lds[65536];   // 128 KiB: A 2buf x 2half x [2 planes][128][32]; B at +32768

    const int z = blockIdx.z;
    const u16* Wp   = (z == 0) ? W0 : (z == 1) ? W1 : (z == 2) ? W2 : W3;
    const float* Bi = (z == 0) ? bi0 : (z == 1) ? bi1 : (z == 2) ? bi2 : bi3;
    u16* Out        = (z == 0) ? O0 : (z == 1) ? O1 : (z == 2) ? O2 : O3;
    const bool act = (actmask >> z) & 1;
    const float osc = ((scalemask >> z) & 1) ? 0.125f : 1.0f;

    const int tid = threadIdx.x;
    const int wid = tid >> 6, lane = tid & 63, quad = lane >> 4, l16 = lane & 15;
    const int wm = wid >> 2, wn = wid & 3;     // 2 M-waves x 4 N-waves
    const int m0 = blockIdx.y * 256;
    const int n0 = blockIdx.x * 256;

    const int swz = ((l16 >> 3) & 1) * 16;
    const int raA = wm * 8192 + l16 * 32 + ((quad * 8) ^ swz);
    const int raB = (wn >> 1) * 8192 + ((wn & 1) * 64 + l16) * 32 + ((quad * 8) ^ swz);

    const int srow_s = tid >> 2;
    const int sce = ((tid & 3) * 8) ^ (((tid >> 5) & 1) * 16);
    const u16* As = A  + (size_t)(m0 + srow_s) * E_ + sce;
    const u16* Bs = Wp + (size_t)(n0 + srow_s) * E_ + sce;

    floatx4 acc[8][4];
    const floatx4 fz = {0.f, 0.f, 0.f, 0.f};
#pragma unroll
    for (int mi = 0; mi < 8; mi++)
#pragma unroll
        for (int bn = 0; bn < 4; bn++) acc[mi][bn] = fz;

    short8 af[8][2], bfr[2][2];

    gll16(As,                  &lds[0     + wid*512]);
    gll16(As + 32,             &lds[4096  + wid*512]);
    gll16(As + 128*E_,         &lds[8192  + wid*512]);
    gll16(As + 128*E_ + 32,    &lds[12288 + wid*512]);
    gll16(Bs,                  &lds[32768 +  0    + wid*512]);
    gll16(Bs + 32,             &lds[32768 + 4096  + wid*512]);
    gll16(Bs + 128*E_,         &lds[32768 + 8192  + wid*512]);
    gll16(Bs + 128*E_ + 32,    &lds[32768 + 12288 + wid*512]);
    gll16(As + 64,             &lds[16384 +  0    + wid*512]);
    gll16(As + 96,             &lds[16384 + 4096  + wid*512]);
    gll16(As + 128*E_ + 64,    &lds[16384 + 8192  + wid*512]);
    gll16(As + 128*E_ + 96,    &lds[16384 + 12288 + wid*512]);
    asm volatile("s_waitcnt vmcnt(4)" ::: "memory");
    __builtin_amdgcn_s_barrier();

    for (int tt = 0; tt < NTILES; tt += 2) {
        TILE(tt, 0);
        TILE(tt + 1, 1);
    }

    float bias_v[4];
#pragma unroll
    for (int bn = 0; bn < 4; bn++) bias_v[bn] = Bi[n0 + wn * 64 + bn * 16 + l16];

#pragma unroll
    for (int mi = 0; mi < 8; mi++) {
        const int row = m0 + wm * 128 + mi * 16 + quad * 4;
#pragma unroll
        for (int bn = 0; bn < 4; bn++) {
            const int col = n0 + wn * 64 + bn * 16 + l16;
#pragma unroll
            for (int r = 0; r < 4; r++) {
                float v = acc[mi][bn][r] + bias_v[bn];
                if (act) v = silu_f(v);
                v *= osc;
                Out[(size_t)(row + r) * E_ + col] = f2bf(v);
            }
        }
    }
}

// ---------------------------------------------------------------------------
// Output projection GEMM v2: 64x128 tile, 512 blocks (2/CU), now with a
// 3-buffer 2-deep pipeline (T3-minimal + T4 counted vmcnt): STAGE(t+2) is
// issued each iteration and vmcnt(3) (never 0 mid-loop) + raw s_barrier keep
// 2 tiles in flight, hiding the ~500-900cy load latency under 2 iterations
// of compute. (Old version: __syncthreads drained vmcnt(0) every K-step ->
// serial latency chain, ~40 us for 8.6 GF.)
// Lifetimes: at end of iter t, outstanding = {t+1(3), t+2(3)}; vmcnt(3)
// forces t+1 landed (what iter t+1 reads). bufs t,t+1,t+2 mod 3 distinct.
// ---------------------------------------------------------------------------
__launch_bounds__(256, 2)
__global__ void gemm_out(const u16* __restrict__ A, const u16* __restrict__ W,
                         const float* __restrict__ Bi, float* __restrict__ Out,
                         int K)
{
    __shared__ u16 a_lds[3][64 * 32];    // 3 x 4 KB
    __shared__ u16 b_lds[3][128 * 32];   // 3 x 8 KB  -> 36 KB total

    const int t    = threadIdx.x;
    const int wave = t >> 6, lane = t & 63, quad = lane >> 4, l16 = lane & 15;
    const int m0 = blockIdx.y * 64;
    const int n0 = blockIdx.x * 128;

    floatx4 acc[4][2];
    const floatx4 fz = {0.f, 0.f, 0.f, 0.f};
    for (int i = 0; i < 4; i++)
        for (int j = 0; j < 2; j++) acc[i][j] = fz;

    const int ar = t >> 2;
    const int ac = (t & 3) * 8;
    const u16* Ag0 = A + (size_t)(m0 + ar) * K + ac;
    const u16* Bg0 = W + (size_t)(n0 + ar) * K + ac;
    const u16* Bg1 = W + (size_t)(n0 + 64 + ar) * K + ac;

    const int nt = K / 32;

#define GO_STAGE(tt, bi) {                                      \
        gll16(Ag0 + (tt) * 32, &a_lds[bi][wave * 512]);         \
        gll16(Bg0 + (tt) * 32, &b_lds[bi][wave * 512]);         \
        gll16(Bg1 + (tt) * 32, &b_lds[bi][2048 + wave * 512]); }

    GO_STAGE(0, 0);
    GO_STAGE(1, 1);
    asm volatile("s_waitcnt vmcnt(3)" ::: "memory");   // tile 0 landed
    __builtin_amdgcn_s_barrier();

    for (int tt = 0; tt < nt; tt++) {
        const int bi = tt % 3;
        if (tt + 2 < nt) {
            const int b2 = (tt + 2) % 3;
            GO_STAGE(tt + 2, b2);
        }
        short8 af[4], bfr[2];
#pragma unroll
        for (int i = 0; i < 4; i++)
            af[i]  = *(const short8*)&a_lds[bi][(i * 16 + l16) * 32 + quad * 8];
#pragma unroll
        for (int j = 0; j < 2; j++)
            bfr[j] = *(const short8*)&b_lds[bi][(wave * 32 + j * 16 + l16) * 32 + quad * 8];
#pragma unroll
        for (int i = 0; i < 4; i++)
#pragma unroll
            for (int j = 0; j < 2; j++)
                acc[i][j] = __builtin_amdgcn_mfma_f32_16x16x32_bf16(af[i], bfr[j], acc[i][j], 0, 0, 0);
        if (tt + 2 < nt) {
            asm volatile("s_waitcnt vmcnt(3)" ::: "memory");   // t+1 landed
        } else {
            asm volatile("s_waitcnt vmcnt(0)" ::: "memory");   // tail drain
        }
        __builtin_amdgcn_s_barrier();
    }
#undef GO_STAGE

    float bias_v[2];
    for (int j = 0; j < 2; j++) bias_v[j] = Bi[n0 + wave * 32 + j * 16 + l16];

    for (int i = 0; i < 4; i++) {
        const int row = m0 + i * 16 + quad * 4;
        for (int j = 0; j < 2; j++) {
            const int col = n0 + wave * 32 + j * 16 + l16;
            for (int r = 0; r < 4; r++)
                Out[(size_t)(row + r) * E_ + col] = acc[i][j][r] + bias_v[j];
        }
    }
}

// ---------------------------------------------------------------------------
// Attention v7: O = relu(Q K^T) @ V, Q pre-scaled 1/8. KSPLIT=2.
// T14 async-STAGE split + LDS double-buffer: per 64-key tile, issue tile
// t+1's global loads BEFORE compute(t) (latency hides under ~650cy of
// MFMA/VALU), ds_write them into buf^1 AFTER compute(t). One __syncthreads
// per tile (was 2); its implicit vmcnt(0) is free (loads already consumed
// by the tail ds_write) and its lgkm drain provides write visibility.
// Evidence this is the right lever: attn time identical at KSPLIT=2 and 4
// (occupancy/BW insensitive) -> per-block serial critical path dominated by
// the naked global-load latency between the two barriers.
// QK: S^T = K Q^T (x32), K rows ROW-PERMUTED (LK=72) so two 16-key C-tiles
// relu_pack in-register into the exact x32 PV A-frag.
// ---------------------------------------------------------------------------
#define LK 72
#define LV 72
#define KSPLIT 2
#define KCHUNK (N_ / KSPLIT)    // 1024 keys per z
#define NKT (KCHUNK / 64)       // 16 tiles

__launch_bounds__(256, 2)
__global__ void attn(const u16* __restrict__ Q, const u16* __restrict__ Kk,
                     const u16* __restrict__ V,
                     u16* __restrict__ P0, u16* __restrict__ P1)
{
    __shared__ u16 k_lds[2][64 * LK];    // row-permuted [keyslot][d], dbuf
    __shared__ u16 v_lds[2][64 * LV];    // [d][key], padded stride, dbuf

    const int bh = blockIdx.y;
    const int b = bh >> 4, h = bh & 15;
    const int z = blockIdx.z;
    u16* __restrict__ Oa = (z == 0) ? P0 : P1;
    const int key_base = z * KCHUNK;

    const int t = threadIdx.x;
    const int wave = t >> 6, lane = t & 63, quad = lane >> 4, l16 = lane & 15;
    const int q0 = blockIdx.x * 256 + wave * 64;
    const size_t base = (size_t)b * N_ * E_ + h * HD_;

    short8 aq[4][2];
    for (int mi = 0; mi < 4; mi++)
        for (int ks = 0; ks < 2; ks++)
            aq[mi][ks] = *(const short8*)(Q + base + (size_t)(q0 + mi * 16 + l16) * E_ + ks * 32 + quad * 8);

    floatx4 o[4][4];
    const floatx4 fz = {0.f, 0.f, 0.f, 0.f};
    for (int mi = 0; mi < 4; mi++)
        for (int nd = 0; nd < 4; nd++) o[mi][nd] = fz;

    const int srow = t >> 2, sseg = (t & 3) * 16;
    const int prow = (srow & 32) + (((srow >> 2) & 1) << 4)
                   + (((srow >> 3) & 3) << 2) + (srow & 3);
    const u16* Ksrc = Kk + base + (size_t)(key_base + srow) * E_ + sseg;
    const u16* Vsrc = V + base + (size_t)(key_base + srow) * E_ + sseg;
    const int kofs = prow * LK + sseg;

    // prologue: tile 0 -> regs -> buf0
    intx4 kv0 = *(const intx4*)(Ksrc);
    intx4 kv1 = *(const intx4*)(Ksrc + 8);
    intx4 vv0 = *(const intx4*)(Vsrc);
    intx4 vv1 = *(const intx4*)(Vsrc + 8);
    {
        *(intx4*)(&k_lds[0][kofs])     = kv0;
        *(intx4*)(&k_lds[0][kofs + 8]) = kv1;
        const u16* v0p = (const u16*)&vv0;
        const u16* v1p = (const u16*)&vv1;
        for (int i = 0; i < 8; i++) {
            v_lds[0][(sseg + i) * LV + srow]     = v0p[i];
            v_lds[0][(sseg + 8 + i) * LV + srow] = v1p[i];
        }
    }

    for (int kt = 0; kt < NKT; kt++) {
        __syncthreads();    // buf[kt&1] writes visible; prev reads of buf^1 done
        const int cur = kt & 1;

        // issue next tile's global loads NOW (hide under compute)
        if (kt + 1 < NKT) {
            const u16* kg = Ksrc + (size_t)((kt + 1) * 64) * E_;
            const u16* vg = Vsrc + (size_t)((kt + 1) * 64) * E_;
            kv0 = *(const intx4*)(kg);
            kv1 = *(const intx4*)(kg + 8);
            vv0 = *(const intx4*)(vg);
            vv1 = *(const intx4*)(vg + 8);
        }

        for (int g = 0; g < 2; g++) {   // 32-key group
            short8 ka[2][2];
            for (int tp = 0; tp < 2; tp++)
                for (int ks = 0; ks < 2; ks++)
                    ka[tp][ks] = *(const short8*)&k_lds[cur][(g * 32 + tp * 16 + l16) * LK + ks * 32 + quad * 8];
            short8 bv[4];
            for (int nd = 0; nd < 4; nd++)
                bv[nd] = *(const short8*)&v_lds[cur][(nd * 16 + l16) * LV + g * 32 + quad * 8];

            for (int mi = 0; mi < 4; mi++) {
                floatx4 c0 = __builtin_amdgcn_mfma_f32_16x16x32_bf16(ka[0][0], aq[mi][0], fz, 0, 0, 0);
                c0 = __builtin_amdgcn_mfma_f32_16x16x32_bf16(ka[0][1], aq[mi][1], c0, 0, 0, 0);
                floatx4 c1 = __builtin_amdgcn_mfma_f32_16x16x32_bf16(ka[1][0], aq[mi][0], fz, 0, 0, 0);
                c1 = __builtin_amdgcn_mfma_f32_16x16x32_bf16(ka[1][1], aq[mi][1], c1, 0, 0, 0);
                union { short4v h[2]; short8 s8; } sf;
                sf.h[0] = relu_pack(c0);
                sf.h[1] = relu_pack(c1);
                for (int nd = 0; nd < 4; nd++)
                    o[mi][nd] = __builtin_amdgcn_mfma_f32_16x16x32_bf16(sf.s8, bv[nd], o[mi][nd], 0, 0, 0);
            }
        }

        // write next tile into buf^1 (its prior readers finished before this
        // iteration's top barrier)
        if (kt + 1 < NKT) {
            const int nxt = cur ^ 1;
            *(intx4*)(&k_lds[nxt][kofs])     = kv0;
            *(intx4*)(&k_lds[nxt][kofs + 8]) = kv1;
            const u16* v0p = (const u16*)&vv0;
            const u16* v1p = (const u16*)&vv1;
            for (int i = 0; i < 8; i++) {
                v_lds[nxt][(sseg + i) * LV + srow]     = v0p[i];
                v_lds[nxt][(sseg + 8 + i) * LV + srow] = v1p[i];
            }
        }
    }

    for (int mi = 0; mi < 4; mi++)
        for (int nd = 0; nd < 4; nd++)
            for (int r = 0; r < 4; r++)
                Oa[(size_t)(b * N_ + q0 + mi * 16 + quad * 4 + r) * E_ + h * HD_ + nd * 16 + l16] =
                    f2bf(o[mi][nd][r]);
}

// ---------------------------------------------------------------------------
// LayerNorm over E=1024 of (P0+P1) + gate by u, emit bf16. 1 block/row.
// ---------------------------------------------------------------------------
__launch_bounds__(256, 4)
__global__ void ln_gate(const u16* __restrict__ P0, const u16* __restrict__ P1,
                        const u16* __restrict__ U,
                        const float* __restrict__ G, const float* __restrict__ Bb,
                        u16* __restrict__ Out)
{
    const int row = blockIdx.x;
    const int t = threadIdx.x;
    const size_t idx = (size_t)row * E_ + t * 4;
    const short4v a0 = *(const short4v*)(P0 + idx);
    const short4v a1 = *(const short4v*)(P1 + idx);
    floatx4 v;
    for (int i = 0; i < 4; i++)
        v[i] = bf2f((u16)a0[i]) + bf2f((u16)a1[i]);
    float s  = v[0] + v[1] + v[2] + v[3];
    float ss = v[0] * v[0] + v[1] * v[1] + v[2] * v[2] + v[3] * v[3];
    for (int off = 32; off; off >>= 1) {
        s  += __shfl_down(s, off, 64);
        ss += __shfl_down(ss, off, 64);
    }
    __shared__ float red[8];
    const int wave = t >> 6, lane = t & 63;
    if (lane == 0) { red[wave] = s; red[4 + wave] = ss; }
    __syncthreads();
    const float S  = red[0] + red[1] + red[2] + red[3];
    const float SS = red[4] + red[5] + red[6] + red[7];
    const float mu  = S * (1.f / E_);
    const float var = SS * (1.f / E_) - mu * mu;
    const float rstd = rsqrtf(var + 1e-5f);

    short4v outv;
    for (int i = 0; i < 4; i++) {
        const int e = t * 4 + i;
        float y = (v[i] - mu) * rstd * G[e] + Bb[e];
        y *= bf2f(U[idx + i]);
        outv[i] = (short)f2bf(y);
    }
    *(short4v*)(Out + idx) = outv;
}

// ---------------------------------------------------------------------------
extern "C" void kernel_launch(void* const* d_in, const int* in_sizes, int n_in,
                              void* d_out, int out_size, void* d_ws, size_t ws_size,
                              hipStream_t stream)
{
    const float* x   = (const float*)d_in[0];
    const float* Wq  = (const float*)d_in[1];
    const float* bq  = (const float*)d_in[2];
    const float* Wk  = (const float*)d_in[3];
    const float* bk  = (const float*)d_in[4];
    const float* Wv  = (const float*)d_in[5];
    const float* bv  = (const float*)d_in[6];
    const float* Wu  = (const float*)d_in[7];
    const float* bu  = (const float*)d_in[8];
    const float* Wo  = (const float*)d_in[9];
    const float* bo  = (const float*)d_in[10];
    const float* lng = (const float*)d_in[11];
    const float* lnb = (const float*)d_in[12];

    char* ws = (char*)d_ws;
    u16*  qw  = (u16*)(ws);                      // 8 MB (q row-major, pre-scaled 1/8)
    u16*  kw  = (u16*)(ws + 8388608);            // 8 MB (K row-major)
    u16*  vw  = (u16*)(ws + 16777216);           // 8 MB (V row-major)
    u16*  uw  = (u16*)(ws + 25165824);           // 8 MB (u row-major)
    u16*  p0  = (u16*)(ws + 33554432);           // 8 MB bf16 attn partial z=0
    u16*  p1  = (u16*)(ws + 41943040);           // 8 MB bf16 attn partial z=1
    u16*  xb  = (u16*)(ws + 50331648);           // 8 MB x->bf16
    u16*  wbq = (u16*)(ws + 58720256);           // 2 MB each, bf16 weights
    u16*  wbk = (u16*)(ws + 60817408);
    u16*  wbv = (u16*)(ws + 62914560);
    u16*  wbu = (u16*)(ws + 65011712);
    u16*  wbo = (u16*)(ws + 67108864);
    u16*  gw  = (u16*)(ws);                      // reuses q buffer after attn

    float* out = (float*)d_out;

    // dtype prep (x + 5 weights, one launch)
    cvt6<<<dim3(M_TOT * E_ / 2048, 1, 6), dim3(256, 1, 1), 0, stream>>>(
        x, Wq, Wk, Wv, Wu, Wo, xb, wbq, wbk, wbv, wbu, wbo);
    // q,k,v,u projections, 256x256 8-phase (silu on v,u; q scaled 1/8)
    gemm8p<<<dim3(E_ / 256, M_TOT / 256, 4), dim3(512, 1, 1), 0, stream>>>(
        xb, wbq, wbk, wbv, wbu, bq, bk, bv, bu, qw, kw, vw, uw, 0xC, 0x1);
    // attention v7: async-stage dbuf, 256q blocks, key-split x2, x32 PV
    attn<<<dim3(N_ / 256, B_ * H_, KSPLIT), dim3(256, 1, 1), 0, stream>>>(qw, kw, vw, p0, p1);
    // layernorm(sum of 2 partials) + gate
    ln_gate<<<dim3(M_TOT, 1, 1), dim3(256, 1, 1), 0, stream>>>(p0, p1, uw, lng, lnb, gw);
    // output projection -> fp32 d_out: 64x128 tiles, 3-buf pipelined
    gemm_out<<<dim3(E_ / 128, M_TOT / 64, 1), dim3(256, 1, 1), 0, stream>>>(gw, wbo, bo, out, E_);
}